// Round 8
// baseline (6603.407 us; speedup 1.0000x reference)
//
#include <hip/hip_runtime.h>

#define T_LEN 8192
#define N_NODES 33
#define N_EDGES 64
#define DIM_IN 3
#define D_H 64
#define D_LSTM 128
#define N_CLS 5
#define TB 4   // timesteps per block in kernel 1

typedef float v2f __attribute__((ext_vector_type(2)));
typedef float v4f __attribute__((ext_vector_type(4)));

// ---------------------------------------------------------------------------
// Kernel 1: graph conv x2 + relu + mean over nodes + input-side LSTM projection
// Writes A in (T, 128, 4) layout: A[(t*128+q)*4 + g] = gate g of unit q
// (g: 0=i, 1=f, 2=g, 3=o), so the LSTM prefetch is ONE dwordx4 per thread.
// ---------------------------------------------------------------------------
__global__ __launch_bounds__(64, 2) void gnn_proj_kernel(
    const float* __restrict__ x,        // (T,33,3)
    const int*   __restrict__ esrc,     // (64,)
    const int*   __restrict__ edst,     // (64,)
    const float* __restrict__ W_rel1,   // (64,3)
    const float* __restrict__ b_rel1,   // (64,)
    const float* __restrict__ W_root1,  // (64,3)
    const float* __restrict__ W_rel2,   // (64,64)
    const float* __restrict__ b_rel2,   // (64,)
    const float* __restrict__ W_root2,  // (64,64)
    const float* __restrict__ W_ih,     // (512,64)
    const float* __restrict__ b_ih,     // (512,)
    const float* __restrict__ b_hh,     // (512,)
    float* __restrict__ A)              // (T,128,4)  [workspace]
{
    const int t0 = blockIdx.x * TB;
    const int j  = threadIdx.x;   // 0..63

    __shared__ __align__(16) float x_s[N_NODES][DIM_IN];
    __shared__ __align__(16) float agg1[N_NODES][DIM_IN];
    __shared__ __align__(16) float h1[N_NODES][D_H];
    __shared__ __align__(16) float agg2[N_NODES][D_H];
    __shared__ __align__(16) float seq_s[TB][D_H];
    __shared__ int es[N_EDGES], ed[N_EDGES];

    es[j] = esrc[j];
    ed[j] = edst[j];

    const float wr1_0 = W_rel1[j*3+0], wr1_1 = W_rel1[j*3+1], wr1_2 = W_rel1[j*3+2];
    const float wt1_0 = W_root1[j*3+0], wt1_1 = W_root1[j*3+1], wt1_2 = W_root1[j*3+2];
    const float br1 = b_rel1[j];
    const float br2 = b_rel2[j];

    float wr2[D_H], wt2[D_H];
    #pragma unroll
    for (int k = 0; k < D_H; ++k) {
        wr2[k] = W_rel2[j*D_H + k];
        wt2[k] = W_root2[j*D_H + k];
    }

    for (int tt = 0; tt < TB; ++tt) {
        const int t = t0 + tt;
        __syncthreads();

        const float* xt = x + (size_t)t * (N_NODES * DIM_IN);
        for (int i = j; i < N_NODES * DIM_IN; i += 64) x_s[0][i] = xt[i];
        __syncthreads();

        if (j < N_NODES) {
            float a0 = 0.f, a1 = 0.f, a2 = 0.f;
            for (int e = 0; e < N_EDGES; ++e) {
                if (ed[e] == j) {
                    a0 += x_s[es[e]][0];
                    a1 += x_s[es[e]][1];
                    a2 += x_s[es[e]][2];
                }
            }
            agg1[j][0] = a0; agg1[j][1] = a1; agg1[j][2] = a2;
        }
        __syncthreads();

        for (int n = 0; n < N_NODES; ++n) {
            float v = br1
                + agg1[n][0]*wr1_0 + agg1[n][1]*wr1_1 + agg1[n][2]*wr1_2
                + x_s[n][0]*wt1_0  + x_s[n][1]*wt1_1  + x_s[n][2]*wt1_2;
            h1[n][j]  = v;
            agg2[n][j] = 0.f;
        }
        __syncthreads();

        for (int e = 0; e < N_EDGES; ++e) {
            agg2[ed[e]][j] += h1[es[e]][j];
        }
        __syncthreads();

        float seqv = 0.f;
        for (int n = 0; n < N_NODES; ++n) {
            const float4* ag4 = (const float4*)agg2[n];
            const float4* h4  = (const float4*)h1[n];
            float acc0 = br2, acc1 = 0.f, acc2 = 0.f, acc3 = 0.f;
            #pragma unroll
            for (int k4 = 0; k4 < D_H/4; ++k4) {
                float4 av = ag4[k4];
                float4 hv = h4[k4];
                acc0 += av.x * wr2[4*k4+0] + hv.x * wt2[4*k4+0];
                acc1 += av.y * wr2[4*k4+1] + hv.y * wt2[4*k4+1];
                acc2 += av.z * wr2[4*k4+2] + hv.z * wt2[4*k4+2];
                acc3 += av.w * wr2[4*k4+3] + hv.w * wt2[4*k4+3];
            }
            float acc = (acc0 + acc1) + (acc2 + acc3);
            seqv += fmaxf(acc, 0.f);
        }
        seq_s[tt][j] = seqv * (1.0f / 33.0f);
    }
    __syncthreads();

    #pragma unroll
    for (int m = 0; m < 8; ++m) {
        const int o = m * 64 + j;
        const float bias = b_ih[o] + b_hh[o];
        const float4* w4 = (const float4*)(W_ih + (size_t)o * D_H);
        float acc[TB];
        #pragma unroll
        for (int tt = 0; tt < TB; ++tt) acc[tt] = bias;
        #pragma unroll
        for (int k4 = 0; k4 < D_H/4; ++k4) {
            float4 wv = w4[k4];
            #pragma unroll
            for (int tt = 0; tt < TB; ++tt) {
                const float4* s4 = (const float4*)seq_s[tt];
                float4 sv = s4[k4];
                acc[tt] += sv.x*wv.x + sv.y*wv.y + sv.z*wv.z + sv.w*wv.w;
            }
        }
        // (T,128,4) layout: q = o&127, g = o>>7
        #pragma unroll
        for (int tt = 0; tt < TB; ++tt) {
            A[((size_t)(t0 + tt) * 128 + (o & 127)) * 4 + (o >> 7)] = acc[tt];
        }
    }
}

// ---------------------------------------------------------------------------
// Kernel 2: sequential LSTM, single block (1 CU), 512 threads = 8 waves,
// 2 waves/SIMD.  Thread (q, kq): all 4 gate rows of h_q x K-chunk
// [32*kq, 32*kq+32).  Weights as 64 named v2f (128 VGPRs).
//
// KEY (round-8 fix): the weight operand of each v_pk_fma_f32 asm is TIED
// ("+v") — the asm redefines the weight into an arch VGPR every iteration
// and the next iteration consumes that SSA value as "v".  The allocator
// therefore CANNOT home weights in AGPRs with copy-per-use (rounds 3-7
// failure mode), cannot rematerialize the loads, cannot sink them.
//
// K-reduce = 2 quad_perm DPP stages. Nonlinearity quad-replicated (no
// divergence); kq==0 writes h. h LDS layout interleaved (conflict-free,
// verified r6); ONE barrier/step. A prefetch = ONE dwordx4 per thread.
// ---------------------------------------------------------------------------
__device__ __forceinline__ float sigmoid_f(float v) {
    return 1.0f / (1.0f + __expf(-v));
}
__device__ __forceinline__ float tanh_f(float v) {
    return 1.0f - 2.0f / (1.0f + __expf(2.0f * v));
}

__device__ __forceinline__ float qp_add_x1(float v) {   // lane ^ 1
    int s = __builtin_amdgcn_update_dpp(0, __float_as_int(v), 0xB1, 0xf, 0xf, true);
    return v + __int_as_float(s);
}
__device__ __forceinline__ float qp_add_x2(float v) {   // lane ^ 2
    int s = __builtin_amdgcn_update_dpp(0, __float_as_int(v), 0x4E, 0xf, 0xf, true);
    return v + __int_as_float(s);
}
__device__ __forceinline__ float red4(float v) {
    return qp_add_x2(qp_add_x1(v));
}

// packed FMA with TIED weight: acc.xy += h.xy * w.xy
// %0=acc (tied), %1=w (tied -> forced arch-VGPR home, loop-carried through
// the asm), %2=h (input)
#define PKFMA(acc, h, w) \
    asm("v_pk_fma_f32 %0, %2, %1, %0" : "+v"(acc), "+v"(w) : "v"(h))

#define R16(M) M(0) M(1) M(2) M(3) M(4) M(5) M(6) M(7) \
               M(8) M(9) M(10) M(11) M(12) M(13) M(14) M(15)

__global__ __launch_bounds__(512, 2)
__attribute__((amdgpu_waves_per_eu(2, 2)))
void lstm_kernel(
    const float* __restrict__ A,      // (T,128,4)
    const float* __restrict__ W_hh,   // (512,128)
    const float* __restrict__ W_fc,   // (5,128)
    const float* __restrict__ b_fc,   // (5,)
    float* __restrict__ out)          // (5,)
{
    const int tid  = threadIdx.x;            // 0..511
    const int wave = tid >> 6;               // 0..7
    const int kq   = tid & 3;                // quad lane = K-chunk id
    const int idx  = (tid >> 2) & 15;
    const int q    = wave * 16 + idx;        // h index 0..127
    const int kbase = kq * 32;               // K-chunk start

    __shared__ __align__(16) float h_s[2][D_LSTM];   // interleaved layout, dbuf

    // ---- weights: 4 gate rows x 32 K = 64 named v2f (128 VGPRs) ----
    const v2f* Wi2 = (const v2f*)(W_hh + (size_t)q          * D_LSTM + kbase);
    const v2f* Wf2 = (const v2f*)(W_hh + (size_t)(128 + q)  * D_LSTM + kbase);
    const v2f* Wg2 = (const v2f*)(W_hh + (size_t)(256 + q)  * D_LSTM + kbase);
    const v2f* Wo2 = (const v2f*)(W_hh + (size_t)(384 + q)  * D_LSTM + kbase);
#define DECLW(i) v2f wi##i = Wi2[i]; v2f wf##i = Wf2[i]; \
                 v2f wg##i = Wg2[i]; v2f wo##i = Wo2[i];
    R16(DECLW)
#undef DECLW

    if (tid < 2 * D_LSTM) ((float*)h_s)[tid] = 0.f;   // h_{-1} = 0 (both bufs)
    __syncthreads();

    float c = 0.f;                      // replicated across the quad

    // prefetch A[0]; one float4 per thread; Ap tracks the NEXT row
    const v4f* A4 = (const v4f*)A;
    const v4f* Aq = A4 + q;
    v4f an = Aq[0];
    const v4f* Ap = Aq + 128;           // row 1

    for (int t = 0; t < T_LEN; ++t) {
        const v4f a_c = an;
        an = Ap[0];                               // prefetch next step
        Ap = (t == T_LEN - 2) ? Aq : Ap + 128;    // wrap keeps loads in-bounds

        // ---- conflict-free broadcast reads of this thread's h chunk ----
        const v4f* hb = (const v4f*)h_s[t & 1];
        v4f hv0 = hb[0*4 + kq];
        v4f hv1 = hb[1*4 + kq];
        v4f hv2 = hb[2*4 + kq];
        v4f hv3 = hb[3*4 + kq];
        v4f hv4 = hb[4*4 + kq];
        v4f hv5 = hb[5*4 + kq];
        v4f hv6 = hb[6*4 + kq];
        v4f hv7 = hb[7*4 + kq];

        // halves as v2f (subregister extracts, no moves)
        v2f h0  = __builtin_shufflevector(hv0, hv0, 0, 1);
        v2f h1  = __builtin_shufflevector(hv0, hv0, 2, 3);
        v2f h2  = __builtin_shufflevector(hv1, hv1, 0, 1);
        v2f h3  = __builtin_shufflevector(hv1, hv1, 2, 3);
        v2f h4  = __builtin_shufflevector(hv2, hv2, 0, 1);
        v2f h5  = __builtin_shufflevector(hv2, hv2, 2, 3);
        v2f h6  = __builtin_shufflevector(hv3, hv3, 0, 1);
        v2f h7  = __builtin_shufflevector(hv3, hv3, 2, 3);
        v2f h8  = __builtin_shufflevector(hv4, hv4, 0, 1);
        v2f h9  = __builtin_shufflevector(hv4, hv4, 2, 3);
        v2f h10 = __builtin_shufflevector(hv5, hv5, 0, 1);
        v2f h11 = __builtin_shufflevector(hv5, hv5, 2, 3);
        v2f h12 = __builtin_shufflevector(hv6, hv6, 0, 1);
        v2f h13 = __builtin_shufflevector(hv6, hv6, 2, 3);
        v2f h14 = __builtin_shufflevector(hv7, hv7, 0, 1);
        v2f h15 = __builtin_shufflevector(hv7, hv7, 2, 3);

        // ---- 64 packed FMAs: 4 gates x 32 K ----
        v2f ci = {0.f, 0.f}, cf = {0.f, 0.f}, cg = {0.f, 0.f}, co = {0.f, 0.f};
#define PK4(i) PKFMA(ci, h##i, wi##i); PKFMA(cf, h##i, wf##i); \
               PKFMA(cg, h##i, wg##i); PKFMA(co, h##i, wo##i);
        R16(PK4)
#undef PK4

        // ---- fold packed halves + K-reduce over the quad (DPP) ----
        const float gi = a_c.x + red4(ci.x + ci.y);
        const float gf = a_c.y + red4(cf.x + cf.y);
        const float gg = a_c.z + red4(cg.x + cg.y);
        const float go = a_c.w + red4(co.x + co.y);

        // ---- nonlinearity: replicated in all quad lanes (no divergence) ----
        const float si = sigmoid_f(gi);
        const float sf = sigmoid_f(gf);
        const float so = sigmoid_f(go);
        const float tg = tanh_f(gg);
        c = sf * c + si * tg;
        const float hv = so * tanh_f(c);

        // only kq==0 writes h_q (interleaved position)
        if (kq == 0) {
            const int cc = q >> 2;                       // chunk 0..31
            const int p  = ((cc & 7) << 2) | (cc >> 3);  // interleaved slot
            h_s[(t + 1) & 1][p * 4 + (q & 3)] = hv;
        }
        __syncthreads();    // ONE barrier per step (dbuf covers W-after-R)
    }

    // final FC: out = hT @ W_fc.T + b_fc  (final h in buffer 0, interleaved)
    if (tid < N_CLS) {
        float acc = b_fc[tid];
        #pragma unroll
        for (int k = 0; k < D_LSTM; ++k) {
            const int cc = k >> 2;
            const int p  = ((cc & 7) << 2) | (cc >> 3);
            acc += h_s[0][p * 4 + (k & 3)] * W_fc[tid * D_LSTM + k];
        }
        out[tid] = acc;
    }
}

// ---------------------------------------------------------------------------
extern "C" void kernel_launch(void* const* d_in, const int* in_sizes, int n_in,
                              void* d_out, int out_size, void* d_ws, size_t ws_size,
                              hipStream_t stream) {
    const float* x       = (const float*)d_in[0];
    const int*   esrc    = (const int*)  d_in[1];
    const int*   edst    = (const int*)  d_in[2];
    const float* W_rel1  = (const float*)d_in[3];
    const float* b_rel1  = (const float*)d_in[4];
    const float* W_root1 = (const float*)d_in[5];
    const float* W_rel2  = (const float*)d_in[6];
    const float* b_rel2  = (const float*)d_in[7];
    const float* W_root2 = (const float*)d_in[8];
    const float* W_ih    = (const float*)d_in[9];
    const float* W_hh    = (const float*)d_in[10];
    const float* b_ih    = (const float*)d_in[11];
    const float* b_hh    = (const float*)d_in[12];
    const float* W_fc    = (const float*)d_in[13];
    const float* b_fc    = (const float*)d_in[14];

    float* out = (float*)d_out;
    float* A   = (float*)d_ws;   // (T,128,4) f32 = 16 MB

    gnn_proj_kernel<<<T_LEN / TB, 64, 0, stream>>>(
        x, esrc, edst, W_rel1, b_rel1, W_root1,
        W_rel2, b_rel2, W_root2, W_ih, b_ih, b_hh, A);

    lstm_kernel<<<1, 512, 0, stream>>>(A, W_hh, W_fc, b_fc, out);
}

// Round 11
// 5821.196 us; speedup vs baseline: 1.1344x; 1.1344x over previous
//
#include <hip/hip_runtime.h>

#define T_LEN 8192
#define N_NODES 33
#define N_EDGES 64
#define DIM_IN 3
#define D_H 64
#define D_LSTM 128
#define N_CLS 5
#define TB 4   // timesteps per block in kernel 1

typedef float v2f __attribute__((ext_vector_type(2)));
typedef float v4f __attribute__((ext_vector_type(4)));

// ---------------------------------------------------------------------------
// Kernel 1: graph conv x2 + relu + mean over nodes + input-side LSTM projection
// Writes A in (T, 128, 4) layout: A[(t*128+q)*4 + g] = gate g of unit q
// (g: 0=i, 1=f, 2=g, 3=o), so the LSTM prefetch is ONE dwordx4 per thread.
// ---------------------------------------------------------------------------
__global__ __launch_bounds__(64, 2) void gnn_proj_kernel(
    const float* __restrict__ x,        // (T,33,3)
    const int*   __restrict__ esrc,     // (64,)
    const int*   __restrict__ edst,     // (64,)
    const float* __restrict__ W_rel1,   // (64,3)
    const float* __restrict__ b_rel1,   // (64,)
    const float* __restrict__ W_root1,  // (64,3)
    const float* __restrict__ W_rel2,   // (64,64)
    const float* __restrict__ b_rel2,   // (64,)
    const float* __restrict__ W_root2,  // (64,64)
    const float* __restrict__ W_ih,     // (512,64)
    const float* __restrict__ b_ih,     // (512,)
    const float* __restrict__ b_hh,     // (512,)
    float* __restrict__ A)              // (T,128,4)  [workspace]
{
    const int t0 = blockIdx.x * TB;
    const int j  = threadIdx.x;   // 0..63

    __shared__ __align__(16) float x_s[N_NODES][DIM_IN];
    __shared__ __align__(16) float agg1[N_NODES][DIM_IN];
    __shared__ __align__(16) float h1[N_NODES][D_H];
    __shared__ __align__(16) float agg2[N_NODES][D_H];
    __shared__ __align__(16) float seq_s[TB][D_H];
    __shared__ int es[N_EDGES], ed[N_EDGES];

    es[j] = esrc[j];
    ed[j] = edst[j];

    const float wr1_0 = W_rel1[j*3+0], wr1_1 = W_rel1[j*3+1], wr1_2 = W_rel1[j*3+2];
    const float wt1_0 = W_root1[j*3+0], wt1_1 = W_root1[j*3+1], wt1_2 = W_root1[j*3+2];
    const float br1 = b_rel1[j];
    const float br2 = b_rel2[j];

    float wr2[D_H], wt2[D_H];
    #pragma unroll
    for (int k = 0; k < D_H; ++k) {
        wr2[k] = W_rel2[j*D_H + k];
        wt2[k] = W_root2[j*D_H + k];
    }

    for (int tt = 0; tt < TB; ++tt) {
        const int t = t0 + tt;
        __syncthreads();

        const float* xt = x + (size_t)t * (N_NODES * DIM_IN);
        for (int i = j; i < N_NODES * DIM_IN; i += 64) x_s[0][i] = xt[i];
        __syncthreads();

        if (j < N_NODES) {
            float a0 = 0.f, a1 = 0.f, a2 = 0.f;
            for (int e = 0; e < N_EDGES; ++e) {
                if (ed[e] == j) {
                    a0 += x_s[es[e]][0];
                    a1 += x_s[es[e]][1];
                    a2 += x_s[es[e]][2];
                }
            }
            agg1[j][0] = a0; agg1[j][1] = a1; agg1[j][2] = a2;
        }
        __syncthreads();

        for (int n = 0; n < N_NODES; ++n) {
            float v = br1
                + agg1[n][0]*wr1_0 + agg1[n][1]*wr1_1 + agg1[n][2]*wr1_2
                + x_s[n][0]*wt1_0  + x_s[n][1]*wt1_1  + x_s[n][2]*wt1_2;
            h1[n][j]  = v;
            agg2[n][j] = 0.f;
        }
        __syncthreads();

        for (int e = 0; e < N_EDGES; ++e) {
            agg2[ed[e]][j] += h1[es[e]][j];
        }
        __syncthreads();

        float seqv = 0.f;
        for (int n = 0; n < N_NODES; ++n) {
            const float4* ag4 = (const float4*)agg2[n];
            const float4* h4  = (const float4*)h1[n];
            float acc0 = br2, acc1 = 0.f, acc2 = 0.f, acc3 = 0.f;
            #pragma unroll
            for (int k4 = 0; k4 < D_H/4; ++k4) {
                float4 av = ag4[k4];
                float4 hv = h4[k4];
                acc0 += av.x * wr2[4*k4+0] + hv.x * wt2[4*k4+0];
                acc1 += av.y * wr2[4*k4+1] + hv.y * wt2[4*k4+1];
                acc2 += av.z * wr2[4*k4+2] + hv.z * wt2[4*k4+2];
                acc3 += av.w * wr2[4*k4+3] + hv.w * wt2[4*k4+3];
            }
            float acc = (acc0 + acc1) + (acc2 + acc3);
            seqv += fmaxf(acc, 0.f);
        }
        seq_s[tt][j] = seqv * (1.0f / 33.0f);
    }
    __syncthreads();

    #pragma unroll
    for (int m = 0; m < 8; ++m) {
        const int o = m * 64 + j;
        const float bias = b_ih[o] + b_hh[o];
        const float4* w4 = (const float4*)(W_ih + (size_t)o * D_H);
        float acc[TB];
        #pragma unroll
        for (int tt = 0; tt < TB; ++tt) acc[tt] = bias;
        #pragma unroll
        for (int k4 = 0; k4 < D_H/4; ++k4) {
            float4 wv = w4[k4];
            #pragma unroll
            for (int tt = 0; tt < TB; ++tt) {
                const float4* s4 = (const float4*)seq_s[tt];
                float4 sv = s4[k4];
                acc[tt] += sv.x*wv.x + sv.y*wv.y + sv.z*wv.z + sv.w*wv.w;
            }
        }
        // (T,128,4) layout: q = o&127, g = o>>7
        #pragma unroll
        for (int tt = 0; tt < TB; ++tt) {
            A[((size_t)(t0 + tt) * 128 + (o & 127)) * 4 + (o >> 7)] = acc[tt];
        }
    }
}

// ---------------------------------------------------------------------------
// Kernel 2: sequential LSTM, single block (1 CU), 512 threads = 8 waves,
// 2 waves/SIMD.  Thread (q, kq): 4 gate rows of h_q x K-chunk [32*kq,+32).
//
// ROUND-11: identical to round 10 except NONLIN is hazard-safe.  CDNA
// requires a software wait state between a TRANS op (v_exp/v_rcp/...) and a
// VALU consumer of its result; round 10 had three zero-gap violations in the
// tanh chains (stale 1+e^{2|gg|} read -> inf -> 0*inf = NaN).  Fix: rcp
// reordering for natural >=3-instr gaps + s_nop 1 where no gap is possible.
//
// Register map:
//   v0..v127   : weights (wi v0-31, wf v32-63, wg v64-95, wo v96-127)
//   v128..v159 : h chunk (8x ds_read_b128)
//   v160..v167 : gate accumulators (4 x v2f)
//   v168..v175 : A prefetch double-buffer (2 x dwordx4)
//   v176..v190 : nonlinearity / reduce temps
//   s80 A-offset, s[82:83] write mask, s[84:85] exec save, s86 loop ctr,
//   s87 = -log2(e), s88 = -2log2(e)
// ---------------------------------------------------------------------------

#define PK4(H0,H1,I0,I1,F0,F1,G0,G1,O0,O1) \
  "v_pk_fma_f32 v[160:161], v[" #H0 ":" #H1 "], v[" #I0 ":" #I1 "], v[160:161]\n\t" \
  "v_pk_fma_f32 v[162:163], v[" #H0 ":" #H1 "], v[" #F0 ":" #F1 "], v[162:163]\n\t" \
  "v_pk_fma_f32 v[164:165], v[" #H0 ":" #H1 "], v[" #G0 ":" #G1 "], v[164:165]\n\t" \
  "v_pk_fma_f32 v[166:167], v[" #H0 ":" #H1 "], v[" #O0 ":" #O1 "], v[166:167]\n\t"

#define FMABLOCK \
  "v_mov_b32 v160, 0\n\t" "v_mov_b32 v161, 0\n\t" \
  "v_mov_b32 v162, 0\n\t" "v_mov_b32 v163, 0\n\t" \
  "v_mov_b32 v164, 0\n\t" "v_mov_b32 v165, 0\n\t" \
  "v_mov_b32 v166, 0\n\t" "v_mov_b32 v167, 0\n\t" \
  PK4(128,129,  0,1,  32,33, 64,65,  96,97)  \
  PK4(130,131,  2,3,  34,35, 66,67,  98,99)  \
  PK4(132,133,  4,5,  36,37, 68,69, 100,101) \
  PK4(134,135,  6,7,  38,39, 70,71, 102,103) \
  PK4(136,137,  8,9,  40,41, 72,73, 104,105) \
  PK4(138,139, 10,11, 42,43, 74,75, 106,107) \
  PK4(140,141, 12,13, 44,45, 76,77, 108,109) \
  PK4(142,143, 14,15, 46,47, 78,79, 110,111) \
  PK4(144,145, 16,17, 48,49, 80,81, 112,113) \
  PK4(146,147, 18,19, 50,51, 82,83, 114,115) \
  PK4(148,149, 20,21, 52,53, 84,85, 116,117) \
  PK4(150,151, 22,23, 54,55, 86,87, 118,119) \
  PK4(152,153, 24,25, 56,57, 88,89, 120,121) \
  PK4(154,155, 26,27, 58,59, 90,91, 122,123) \
  PK4(156,157, 28,29, 60,61, 92,93, 124,125) \
  PK4(158,159, 30,31, 62,63, 94,95, 126,127)

// hazard-safe nonlinearity:
//  si=sigma(gi) v176, sf=sigma(gf) v177, so=sigma(go) v178, tg=tanh(gg) v179
//  c (v181) = sf*c + si*tg ; h (v183) = so*tanh(c)
//  every TRANS result has >=2 intervening instructions or an s_nop 1
#define NONLIN \
  "v_mul_f32 v176, s87, v160\n\t" \
  "v_mul_f32 v177, s87, v162\n\t" \
  "v_mul_f32 v178, s87, v166\n\t" \
  "v_mul_f32 v179, s88, v164\n\t" \
  "v_exp_f32 v176, v176\n\t" \
  "v_exp_f32 v177, v177\n\t" \
  "v_exp_f32 v178, v178\n\t" \
  "v_exp_f32 v179, v179\n\t" \
  "v_add_f32 v176, 1.0, v176\n\t" \
  "v_add_f32 v177, 1.0, v177\n\t" \
  "v_add_f32 v178, 1.0, v178\n\t" \
  "v_add_f32 v179, 1.0, v179\n\t" \
  "v_rcp_f32 v179, v179\n\t" \
  "v_rcp_f32 v176, v176\n\t" \
  "v_rcp_f32 v177, v177\n\t" \
  "v_rcp_f32 v178, v178\n\t" \
  "v_add_f32 v179, v179, v179\n\t" \
  "v_add_f32 v179, -1.0, v179\n\t" \
  "v_mul_f32 v180, v176, v179\n\t" \
  "v_fma_f32 v181, v177, v181, v180\n\t" \
  "v_mul_f32 v182, s88, v181\n\t" \
  "v_exp_f32 v182, v182\n\t" \
  "s_nop 1\n\t" \
  "v_add_f32 v182, 1.0, v182\n\t" \
  "v_rcp_f32 v182, v182\n\t" \
  "s_nop 1\n\t" \
  "v_add_f32 v182, v182, v182\n\t" \
  "v_add_f32 v182, -1.0, v182\n\t" \
  "v_mul_f32 v183, v178, v182\n\t"

#define HALF(P0,P3, R0,R1,R2,R3,R4,R5,R6,R7, A0,A1,A2,A3, WOFF) \
  "v_add_u32 v190, s80, %[at]\n\t" \
  "global_load_dwordx4 v[" #P0 ":" #P3 "], v190, %[ab]\n\t" \
  "s_add_u32 s80, s80, 2048\n\t" \
  "s_cmp_lg_u32 s80, 0x1000000\n\t" \
  "s_cselect_b32 s80, s80, 0\n\t" \
  "ds_read_b128 v[128:131], %[rd] offset:" #R0 "\n\t" \
  "ds_read_b128 v[132:135], %[rd] offset:" #R1 "\n\t" \
  "ds_read_b128 v[136:139], %[rd] offset:" #R2 "\n\t" \
  "ds_read_b128 v[140:143], %[rd] offset:" #R3 "\n\t" \
  "ds_read_b128 v[144:147], %[rd] offset:" #R4 "\n\t" \
  "ds_read_b128 v[148:151], %[rd] offset:" #R5 "\n\t" \
  "ds_read_b128 v[152:155], %[rd] offset:" #R6 "\n\t" \
  "ds_read_b128 v[156:159], %[rd] offset:" #R7 "\n\t" \
  "s_waitcnt lgkmcnt(0)\n\t" \
  FMABLOCK \
  "v_add_f32 v160, v160, v161\n\t" \
  "v_add_f32 v162, v162, v163\n\t" \
  "v_add_f32 v164, v164, v165\n\t" \
  "v_add_f32 v166, v166, v167\n\t" \
  "ds_swizzle_b32 v184, v160 offset:0x041F\n\t" \
  "ds_swizzle_b32 v185, v162 offset:0x041F\n\t" \
  "ds_swizzle_b32 v186, v164 offset:0x041F\n\t" \
  "ds_swizzle_b32 v187, v166 offset:0x041F\n\t" \
  "s_waitcnt lgkmcnt(0)\n\t" \
  "v_add_f32 v160, v160, v184\n\t" \
  "v_add_f32 v162, v162, v185\n\t" \
  "v_add_f32 v164, v164, v186\n\t" \
  "v_add_f32 v166, v166, v187\n\t" \
  "ds_swizzle_b32 v184, v160 offset:0x081F\n\t" \
  "ds_swizzle_b32 v185, v162 offset:0x081F\n\t" \
  "ds_swizzle_b32 v186, v164 offset:0x081F\n\t" \
  "ds_swizzle_b32 v187, v166 offset:0x081F\n\t" \
  "s_waitcnt lgkmcnt(0)\n\t" \
  "v_add_f32 v160, v160, v184\n\t" \
  "v_add_f32 v162, v162, v185\n\t" \
  "v_add_f32 v164, v164, v186\n\t" \
  "v_add_f32 v166, v166, v187\n\t" \
  "s_waitcnt vmcnt(1)\n\t" \
  "v_add_f32 v160, v160, v" #A0 "\n\t" \
  "v_add_f32 v162, v162, v" #A1 "\n\t" \
  "v_add_f32 v164, v164, v" #A2 "\n\t" \
  "v_add_f32 v166, v166, v" #A3 "\n\t" \
  NONLIN \
  "s_and_saveexec_b64 s[84:85], s[82:83]\n\t" \
  "ds_write_b32 %[wr], v183 offset:" #WOFF "\n\t" \
  "s_mov_b64 exec, s[84:85]\n\t" \
  "s_waitcnt lgkmcnt(0)\n\t" \
  "s_barrier\n\t"

__global__ __launch_bounds__(512, 2)
__attribute__((amdgpu_waves_per_eu(2, 2)))
void lstm_kernel(
    const float* __restrict__ A,      // (T,128,4)
    const float* __restrict__ W_hh,   // (512,128)
    const float* __restrict__ W_fc,   // (5,128)
    const float* __restrict__ b_fc,   // (5,)
    float* __restrict__ out)          // (5,)
{
    const int tid  = threadIdx.x;            // 0..511
    const int wave = tid >> 6;               // 0..7
    const int kq   = tid & 3;                // quad lane = K-chunk id
    const int idx  = (tid >> 2) & 15;
    const int q    = wave * 16 + idx;        // h index 0..127
    const int kbase = kq * 32;               // K-chunk start

    __shared__ __align__(16) float h_s[2][D_LSTM];   // interleaved layout, dbuf

    if (tid < 2 * D_LSTM) ((float*)h_s)[tid] = 0.f;  // h_{-1} = 0 (both bufs)
    __syncthreads();

    // per-thread addresses for the asm block
    const unsigned long long wai = (unsigned long long)(uintptr_t)(W_hh + (size_t)q         * D_LSTM + kbase);
    const unsigned long long waf = (unsigned long long)(uintptr_t)(W_hh + (size_t)(128 + q) * D_LSTM + kbase);
    const unsigned long long wag = (unsigned long long)(uintptr_t)(W_hh + (size_t)(256 + q) * D_LSTM + kbase);
    const unsigned long long wao = (unsigned long long)(uintptr_t)(W_hh + (size_t)(384 + q) * D_LSTM + kbase);
    const unsigned int atid = (unsigned int)(q * 16);            // byte off of A float4
    const unsigned int lds0 = (unsigned int)(uintptr_t)&h_s[0][0];
    const unsigned int rd   = lds0 + (unsigned int)(kq * 16);
    const int cc = q >> 2;
    const int p  = ((cc & 7) << 2) | (cc >> 3);                  // interleaved slot
    const unsigned int wr = lds0 + (unsigned int)(p * 16 + (q & 3) * 4);
    const unsigned long long wm = __ballot(kq == 0);

    asm volatile(
        // ---- prologue: consts + weight loads + A row0 ----
        "s_mov_b32 s80, 2048\n\t"
        "s_mov_b32 s86, 4096\n\t"
        "s_mov_b32 s87, 0xBFB8AA3B\n\t"     // -log2(e)
        "s_mov_b32 s88, 0xC038AA3B\n\t"     // -2*log2(e)
        "s_mov_b64 s[82:83], %[wm]\n\t"
        "global_load_dwordx4 v[0:3],     %[wai], off\n\t"
        "global_load_dwordx4 v[4:7],     %[wai], off offset:16\n\t"
        "global_load_dwordx4 v[8:11],    %[wai], off offset:32\n\t"
        "global_load_dwordx4 v[12:15],   %[wai], off offset:48\n\t"
        "global_load_dwordx4 v[16:19],   %[wai], off offset:64\n\t"
        "global_load_dwordx4 v[20:23],   %[wai], off offset:80\n\t"
        "global_load_dwordx4 v[24:27],   %[wai], off offset:96\n\t"
        "global_load_dwordx4 v[28:31],   %[wai], off offset:112\n\t"
        "global_load_dwordx4 v[32:35],   %[waf], off\n\t"
        "global_load_dwordx4 v[36:39],   %[waf], off offset:16\n\t"
        "global_load_dwordx4 v[40:43],   %[waf], off offset:32\n\t"
        "global_load_dwordx4 v[44:47],   %[waf], off offset:48\n\t"
        "global_load_dwordx4 v[48:51],   %[waf], off offset:64\n\t"
        "global_load_dwordx4 v[52:55],   %[waf], off offset:80\n\t"
        "global_load_dwordx4 v[56:59],   %[waf], off offset:96\n\t"
        "global_load_dwordx4 v[60:63],   %[waf], off offset:112\n\t"
        "global_load_dwordx4 v[64:67],   %[wag], off\n\t"
        "global_load_dwordx4 v[68:71],   %[wag], off offset:16\n\t"
        "global_load_dwordx4 v[72:75],   %[wag], off offset:32\n\t"
        "global_load_dwordx4 v[76:79],   %[wag], off offset:48\n\t"
        "global_load_dwordx4 v[80:83],   %[wag], off offset:64\n\t"
        "global_load_dwordx4 v[84:87],   %[wag], off offset:80\n\t"
        "global_load_dwordx4 v[88:91],   %[wag], off offset:96\n\t"
        "global_load_dwordx4 v[92:95],   %[wag], off offset:112\n\t"
        "global_load_dwordx4 v[96:99],   %[wao], off\n\t"
        "global_load_dwordx4 v[100:103], %[wao], off offset:16\n\t"
        "global_load_dwordx4 v[104:107], %[wao], off offset:32\n\t"
        "global_load_dwordx4 v[108:111], %[wao], off offset:48\n\t"
        "global_load_dwordx4 v[112:115], %[wao], off offset:64\n\t"
        "global_load_dwordx4 v[116:119], %[wao], off offset:80\n\t"
        "global_load_dwordx4 v[120:123], %[wao], off offset:96\n\t"
        "global_load_dwordx4 v[124:127], %[wao], off offset:112\n\t"
        "global_load_dwordx4 v[168:171], %[at], %[ab]\n\t"   // A row 0
        "s_waitcnt vmcnt(0)\n\t"
        "v_mov_b32 v181, 0\n\t"             // c = 0
        "1:\n\t"
        // even step: read buf0 (+0), consume a_even v168-171, prefetch odd, write buf1 (+512)
        HALF(172,175, 0,64,128,192,256,320,384,448, 168,169,170,171, 512)
        // odd step: read buf1 (+512), consume a_odd v172-175, prefetch even, write buf0 (+0)
        HALF(168,171, 512,576,640,704,768,832,896,960, 172,173,174,175, 0)
        "s_sub_u32 s86, s86, 1\n\t"
        "s_cmp_lg_u32 s86, 0\n\t"
        "s_cbranch_scc1 1b\n\t"
        :
        : [wai]"v"(wai), [waf]"v"(waf), [wag]"v"(wag), [wao]"v"(wao),
          [ab]"s"(A), [at]"v"(atid), [rd]"v"(rd), [wr]"v"(wr), [wm]"s"(wm)
        : "v0","v1","v2","v3","v4","v5","v6","v7","v8","v9",
          "v10","v11","v12","v13","v14","v15","v16","v17","v18","v19",
          "v20","v21","v22","v23","v24","v25","v26","v27","v28","v29",
          "v30","v31","v32","v33","v34","v35","v36","v37","v38","v39",
          "v40","v41","v42","v43","v44","v45","v46","v47","v48","v49",
          "v50","v51","v52","v53","v54","v55","v56","v57","v58","v59",
          "v60","v61","v62","v63","v64","v65","v66","v67","v68","v69",
          "v70","v71","v72","v73","v74","v75","v76","v77","v78","v79",
          "v80","v81","v82","v83","v84","v85","v86","v87","v88","v89",
          "v90","v91","v92","v93","v94","v95","v96","v97","v98","v99",
          "v100","v101","v102","v103","v104","v105","v106","v107","v108","v109",
          "v110","v111","v112","v113","v114","v115","v116","v117","v118","v119",
          "v120","v121","v122","v123","v124","v125","v126","v127","v128","v129",
          "v130","v131","v132","v133","v134","v135","v136","v137","v138","v139",
          "v140","v141","v142","v143","v144","v145","v146","v147","v148","v149",
          "v150","v151","v152","v153","v154","v155","v156","v157","v158","v159",
          "v160","v161","v162","v163","v164","v165","v166","v167","v168","v169",
          "v170","v171","v172","v173","v174","v175","v176","v177","v178","v179",
          "v180","v181","v182","v183","v184","v185","v186","v187","v188","v189",
          "v190","v191",
          "s80","s81","s82","s83","s84","s85","s86","s87","s88",
          "scc","memory"
    );

    __syncthreads();

    // final FC: out = hT @ W_fc.T + b_fc  (final h in buffer 0, interleaved)
    if (tid < N_CLS) {
        float acc = b_fc[tid];
        #pragma unroll
        for (int k = 0; k < D_LSTM; ++k) {
            const int c2 = k >> 2;
            const int pp = ((c2 & 7) << 2) | (c2 >> 3);
            acc += h_s[0][pp * 4 + (k & 3)] * W_fc[tid * D_LSTM + k];
        }
        out[tid] = acc;
    }
}

// ---------------------------------------------------------------------------
extern "C" void kernel_launch(void* const* d_in, const int* in_sizes, int n_in,
                              void* d_out, int out_size, void* d_ws, size_t ws_size,
                              hipStream_t stream) {
    const float* x       = (const float*)d_in[0];
    const int*   esrc    = (const int*)  d_in[1];
    const int*   edst    = (const int*)  d_in[2];
    const float* W_rel1  = (const float*)d_in[3];
    const float* b_rel1  = (const float*)d_in[4];
    const float* W_root1 = (const float*)d_in[5];
    const float* W_rel2  = (const float*)d_in[6];
    const float* b_rel2  = (const float*)d_in[7];
    const float* W_root2 = (const float*)d_in[8];
    const float* W_ih    = (const float*)d_in[9];
    const float* W_hh    = (const float*)d_in[10];
    const float* b_ih    = (const float*)d_in[11];
    const float* b_hh    = (const float*)d_in[12];
    const float* W_fc    = (const float*)d_in[13];
    const float* b_fc    = (const float*)d_in[14];

    float* out = (float*)d_out;
    float* A   = (float*)d_ws;   // (T,128,4) f32 = 16 MB

    gnn_proj_kernel<<<T_LEN / TB, 64, 0, stream>>>(
        x, esrc, edst, W_rel1, b_rel1, W_root1,
        W_rel2, b_rel2, W_root2, W_ih, b_ih, b_hh, A);

    lstm_kernel<<<1, 512, 0, stream>>>(A, W_hh, W_fc, b_fc, out);
}

// Round 13
// 4665.122 us; speedup vs baseline: 1.4155x; 1.2478x over previous
//
#include <hip/hip_runtime.h>

#define T_LEN 8192
#define N_NODES 33
#define N_EDGES 64
#define DIM_IN 3
#define D_H 64
#define D_LSTM 128
#define N_CLS 5
#define TB 4   // timesteps per block in kernel 1

typedef float v2f __attribute__((ext_vector_type(2)));
typedef float v4f __attribute__((ext_vector_type(4)));

// ---------------------------------------------------------------------------
// Kernel 1: graph conv x2 + relu + mean over nodes + input-side LSTM projection
// Writes A in (T, 128, 4) layout: A[(t*128+q)*4 + g] = gate g of unit q
// (g: 0=i, 1=f, 2=g, 3=o).  LSTM thread (q,kq) scalar-loads its own gate.
// ---------------------------------------------------------------------------
__global__ __launch_bounds__(64, 2) void gnn_proj_kernel(
    const float* __restrict__ x,        // (T,33,3)
    const int*   __restrict__ esrc,     // (64,)
    const int*   __restrict__ edst,     // (64,)
    const float* __restrict__ W_rel1,   // (64,3)
    const float* __restrict__ b_rel1,   // (64,)
    const float* __restrict__ W_root1,  // (64,3)
    const float* __restrict__ W_rel2,   // (64,64)
    const float* __restrict__ b_rel2,   // (64,)
    const float* __restrict__ W_root2,  // (64,64)
    const float* __restrict__ W_ih,     // (512,64)
    const float* __restrict__ b_ih,     // (512,)
    const float* __restrict__ b_hh,     // (512,)
    float* __restrict__ A)              // (T,128,4)  [workspace]
{
    const int t0 = blockIdx.x * TB;
    const int j  = threadIdx.x;   // 0..63

    __shared__ __align__(16) float x_s[N_NODES][DIM_IN];
    __shared__ __align__(16) float agg1[N_NODES][DIM_IN];
    __shared__ __align__(16) float h1[N_NODES][D_H];
    __shared__ __align__(16) float agg2[N_NODES][D_H];
    __shared__ __align__(16) float seq_s[TB][D_H];
    __shared__ int es[N_EDGES], ed[N_EDGES];

    es[j] = esrc[j];
    ed[j] = edst[j];

    const float wr1_0 = W_rel1[j*3+0], wr1_1 = W_rel1[j*3+1], wr1_2 = W_rel1[j*3+2];
    const float wt1_0 = W_root1[j*3+0], wt1_1 = W_root1[j*3+1], wt1_2 = W_root1[j*3+2];
    const float br1 = b_rel1[j];
    const float br2 = b_rel2[j];

    float wr2[D_H], wt2[D_H];
    #pragma unroll
    for (int k = 0; k < D_H; ++k) {
        wr2[k] = W_rel2[j*D_H + k];
        wt2[k] = W_root2[j*D_H + k];
    }

    for (int tt = 0; tt < TB; ++tt) {
        const int t = t0 + tt;
        __syncthreads();

        const float* xt = x + (size_t)t * (N_NODES * DIM_IN);
        for (int i = j; i < N_NODES * DIM_IN; i += 64) x_s[0][i] = xt[i];
        __syncthreads();

        if (j < N_NODES) {
            float a0 = 0.f, a1 = 0.f, a2 = 0.f;
            for (int e = 0; e < N_EDGES; ++e) {
                if (ed[e] == j) {
                    a0 += x_s[es[e]][0];
                    a1 += x_s[es[e]][1];
                    a2 += x_s[es[e]][2];
                }
            }
            agg1[j][0] = a0; agg1[j][1] = a1; agg1[j][2] = a2;
        }
        __syncthreads();

        for (int n = 0; n < N_NODES; ++n) {
            float v = br1
                + agg1[n][0]*wr1_0 + agg1[n][1]*wr1_1 + agg1[n][2]*wr1_2
                + x_s[n][0]*wt1_0  + x_s[n][1]*wt1_1  + x_s[n][2]*wt1_2;
            h1[n][j]  = v;
            agg2[n][j] = 0.f;
        }
        __syncthreads();

        for (int e = 0; e < N_EDGES; ++e) {
            agg2[ed[e]][j] += h1[es[e]][j];
        }
        __syncthreads();

        float seqv = 0.f;
        for (int n = 0; n < N_NODES; ++n) {
            const float4* ag4 = (const float4*)agg2[n];
            const float4* h4  = (const float4*)h1[n];
            float acc0 = br2, acc1 = 0.f, acc2 = 0.f, acc3 = 0.f;
            #pragma unroll
            for (int k4 = 0; k4 < D_H/4; ++k4) {
                float4 av = ag4[k4];
                float4 hv = h4[k4];
                acc0 += av.x * wr2[4*k4+0] + hv.x * wt2[4*k4+0];
                acc1 += av.y * wr2[4*k4+1] + hv.y * wt2[4*k4+1];
                acc2 += av.z * wr2[4*k4+2] + hv.z * wt2[4*k4+2];
                acc3 += av.w * wr2[4*k4+3] + hv.w * wt2[4*k4+3];
            }
            float acc = (acc0 + acc1) + (acc2 + acc3);
            seqv += fmaxf(acc, 0.f);
        }
        seq_s[tt][j] = seqv * (1.0f / 33.0f);
    }
    __syncthreads();

    #pragma unroll
    for (int m = 0; m < 8; ++m) {
        const int o = m * 64 + j;
        const float bias = b_ih[o] + b_hh[o];
        const float4* w4 = (const float4*)(W_ih + (size_t)o * D_H);
        float acc[TB];
        #pragma unroll
        for (int tt = 0; tt < TB; ++tt) acc[tt] = bias;
        #pragma unroll
        for (int k4 = 0; k4 < D_H/4; ++k4) {
            float4 wv = w4[k4];
            #pragma unroll
            for (int tt = 0; tt < TB; ++tt) {
                const float4* s4 = (const float4*)seq_s[tt];
                float4 sv = s4[k4];
                acc[tt] += sv.x*wv.x + sv.y*wv.y + sv.z*wv.z + sv.w*wv.w;
            }
        }
        // (T,128,4) layout: q = o&127, g = o>>7
        #pragma unroll
        for (int tt = 0; tt < TB; ++tt) {
            A[((size_t)(t0 + tt) * 128 + (o & 127)) * 4 + (o >> 7)] = acc[tt];
        }
    }
}

// ---------------------------------------------------------------------------
// Kernel 2 (round 13 = round 12 design, macro fixed): full-asm LSTM, DS pipe
// minimized.
//  - quad reduce-scatter via v_mov_b32_dpp (VALU pipe): xor2 round on all 4
//    gate accs -> mb1-select into (vA=I'/G', vB=F'/O') -> xor1 round ->
//    mb0-select => lane kq holds the FULL sum of gate kq.
//  - per-lane nonlinearity (ONE sigma/tanh per lane: y=rcp(1+exp2(m*x)),
//    y'=fma(y,sc,ad) with per-lane consts), then 4 quad-broadcast mov_dpp.
//  - A is a per-lane SCALAR dword (gate kq of unit q), coalesced.
//  - staged lgkmcnt(4)/(0) so half the FMA block hides read latency.
// Register map: v0-127 weights | v128-159 h | v160-167 accs | v168/v172 A
// dbuf | v176-190 temps | s80 A-off, s[82:83] wmask, s[84:85] exec save,
// s86 ctr, s88 -2log2e.
// r12 lesson: '#' stringification only works on direct macro parameters —
// pass the consume register number PC explicitly.
// ---------------------------------------------------------------------------

#define PKM4(H0,H1,I0,I1,F0,F1,G0,G1,O0,O1) \
  "v_pk_mul_f32 v[160:161], v[" #H0 ":" #H1 "], v[" #I0 ":" #I1 "]\n\t" \
  "v_pk_mul_f32 v[162:163], v[" #H0 ":" #H1 "], v[" #F0 ":" #F1 "]\n\t" \
  "v_pk_mul_f32 v[164:165], v[" #H0 ":" #H1 "], v[" #G0 ":" #G1 "]\n\t" \
  "v_pk_mul_f32 v[166:167], v[" #H0 ":" #H1 "], v[" #O0 ":" #O1 "]\n\t"

#define PK4(H0,H1,I0,I1,F0,F1,G0,G1,O0,O1) \
  "v_pk_fma_f32 v[160:161], v[" #H0 ":" #H1 "], v[" #I0 ":" #I1 "], v[160:161]\n\t" \
  "v_pk_fma_f32 v[162:163], v[" #H0 ":" #H1 "], v[" #F0 ":" #F1 "], v[162:163]\n\t" \
  "v_pk_fma_f32 v[164:165], v[" #H0 ":" #H1 "], v[" #G0 ":" #G1 "], v[164:165]\n\t" \
  "v_pk_fma_f32 v[166:167], v[" #H0 ":" #H1 "], v[" #O0 ":" #O1 "], v[166:167]\n\t"

// blocks for h regs v128-143 (reads 0-3); first group inits via pk_mul
#define FMABLOCK_A \
  PKM4(128,129,  0,1,  32,33, 64,65,  96,97)  \
  PK4(130,131,  2,3,  34,35, 66,67,  98,99)  \
  PK4(132,133,  4,5,  36,37, 68,69, 100,101) \
  PK4(134,135,  6,7,  38,39, 70,71, 102,103) \
  PK4(136,137,  8,9,  40,41, 72,73, 104,105) \
  PK4(138,139, 10,11, 42,43, 74,75, 106,107) \
  PK4(140,141, 12,13, 44,45, 76,77, 108,109) \
  PK4(142,143, 14,15, 46,47, 78,79, 110,111)

// blocks for h regs v144-159 (reads 4-7)
#define FMABLOCK_B \
  PK4(144,145, 16,17, 48,49, 80,81, 112,113) \
  PK4(146,147, 18,19, 50,51, 82,83, 114,115) \
  PK4(148,149, 20,21, 52,53, 84,85, 116,117) \
  PK4(150,151, 22,23, 54,55, 86,87, 118,119) \
  PK4(152,153, 24,25, 56,57, 88,89, 120,121) \
  PK4(154,155, 26,27, 58,59, 90,91, 122,123) \
  PK4(156,157, 28,29, 60,61, 92,93, 124,125) \
  PK4(158,159, 30,31, 62,63, 94,95, 126,127)

// P = prefetch dest reg (next step's A), PC = consume reg (this step's A)
#define HALF(P, PC, R0,R1,R2,R3,R4,R5,R6,R7, WOFF) \
  "v_add_u32 v190, s80, %[at]\n\t" \
  "global_load_dword v" #P ", v190, %[ab]\n\t" \
  "s_add_u32 s80, s80, 2048\n\t" \
  "s_cmp_lg_u32 s80, 0x1000000\n\t" \
  "s_cselect_b32 s80, s80, 0\n\t" \
  "ds_read_b128 v[128:131], %[rd] offset:" #R0 "\n\t" \
  "ds_read_b128 v[132:135], %[rd] offset:" #R1 "\n\t" \
  "ds_read_b128 v[136:139], %[rd] offset:" #R2 "\n\t" \
  "ds_read_b128 v[140:143], %[rd] offset:" #R3 "\n\t" \
  "ds_read_b128 v[144:147], %[rd] offset:" #R4 "\n\t" \
  "ds_read_b128 v[148:151], %[rd] offset:" #R5 "\n\t" \
  "ds_read_b128 v[152:155], %[rd] offset:" #R6 "\n\t" \
  "ds_read_b128 v[156:159], %[rd] offset:" #R7 "\n\t" \
  "s_waitcnt lgkmcnt(4)\n\t" \
  FMABLOCK_A \
  "s_waitcnt lgkmcnt(0)\n\t" \
  FMABLOCK_B \
  /* fold packed halves */ \
  "v_add_f32 v160, v160, v161\n\t" \
  "v_add_f32 v162, v162, v163\n\t" \
  "v_add_f32 v164, v164, v165\n\t" \
  "v_add_f32 v166, v166, v167\n\t" \
  /* quad reduce-scatter round 1: xor2 */ \
  "v_mov_b32_dpp v184, v160 quad_perm:[2,3,0,1] row_mask:0xf bank_mask:0xf\n\t" \
  "v_mov_b32_dpp v185, v162 quad_perm:[2,3,0,1] row_mask:0xf bank_mask:0xf\n\t" \
  "v_mov_b32_dpp v186, v164 quad_perm:[2,3,0,1] row_mask:0xf bank_mask:0xf\n\t" \
  "v_mov_b32_dpp v187, v166 quad_perm:[2,3,0,1] row_mask:0xf bank_mask:0xf\n\t" \
  "v_add_f32 v160, v160, v184\n\t" \
  "v_add_f32 v162, v162, v185\n\t" \
  "v_add_f32 v164, v164, v186\n\t" \
  "v_add_f32 v166, v166, v187\n\t" \
  /* select gate-pair: vA(184)=I'/G', vB(185)=F'/O' by mb1 */ \
  "v_cndmask_b32 v184, v160, v164, %[mb1]\n\t" \
  "v_cndmask_b32 v185, v162, v166, %[mb1]\n\t" \
  "s_nop 1\n\t" \
  /* round 2: xor1 */ \
  "v_mov_b32_dpp v186, v184 quad_perm:[1,0,3,2] row_mask:0xf bank_mask:0xf\n\t" \
  "v_mov_b32_dpp v187, v185 quad_perm:[1,0,3,2] row_mask:0xf bank_mask:0xf\n\t" \
  "v_add_f32 v184, v184, v186\n\t" \
  "v_add_f32 v185, v185, v187\n\t" \
  "v_cndmask_b32 v184, v184, v185, %[mb0]\n\t"   /* lane kq: full sum of gate kq */ \
  /* + A bias (scalar, loaded previous step) */ \
  "s_waitcnt vmcnt(1)\n\t" \
  "v_add_f32 v184, v184, v" #PC "\n\t" \
  /* per-lane nonlin: y=rcp(1+exp2(m1*x)); y'=y*sc+ad */ \
  "v_mul_f32 v186, %[m1], v184\n\t" \
  "v_exp_f32 v186, v186\n\t" \
  "s_nop 1\n\t" \
  "v_add_f32 v186, 1.0, v186\n\t" \
  "v_rcp_f32 v186, v186\n\t" \
  "s_nop 1\n\t" \
  "v_fma_f32 v186, v186, %[sc], %[ad]\n\t" \
  "s_nop 1\n\t" \
  /* quad broadcast: si,sf,tg,so */ \
  "v_mov_b32_dpp v176, v186 quad_perm:[0,0,0,0] row_mask:0xf bank_mask:0xf\n\t" \
  "v_mov_b32_dpp v177, v186 quad_perm:[1,1,1,1] row_mask:0xf bank_mask:0xf\n\t" \
  "v_mov_b32_dpp v179, v186 quad_perm:[2,2,2,2] row_mask:0xf bank_mask:0xf\n\t" \
  "v_mov_b32_dpp v178, v186 quad_perm:[3,3,3,3] row_mask:0xf bank_mask:0xf\n\t" \
  /* c = sf*c + si*tg */ \
  "v_mul_f32 v180, v176, v179\n\t" \
  "v_fma_f32 v181, v177, v181, v180\n\t" \
  /* tanh(c) */ \
  "v_mul_f32 v182, s88, v181\n\t" \
  "v_exp_f32 v182, v182\n\t" \
  "s_nop 1\n\t" \
  "v_add_f32 v182, 1.0, v182\n\t" \
  "v_rcp_f32 v182, v182\n\t" \
  "s_nop 1\n\t" \
  "v_fma_f32 v182, v182, 2.0, -1.0\n\t" \
  "v_mul_f32 v183, v178, v182\n\t" \
  /* write h (kq==0 lanes) */ \
  "s_and_saveexec_b64 s[84:85], s[82:83]\n\t" \
  "ds_write_b32 %[wr], v183 offset:" #WOFF "\n\t" \
  "s_mov_b64 exec, s[84:85]\n\t" \
  "s_waitcnt lgkmcnt(0)\n\t" \
  "s_barrier\n\t"

__global__ __launch_bounds__(512, 2)
__attribute__((amdgpu_waves_per_eu(2, 2)))
void lstm_kernel(
    const float* __restrict__ A,      // (T,128,4)
    const float* __restrict__ W_hh,   // (512,128)
    const float* __restrict__ W_fc,   // (5,128)
    const float* __restrict__ b_fc,   // (5,)
    float* __restrict__ out)          // (5,)
{
    const int tid  = threadIdx.x;            // 0..511
    const int wave = tid >> 6;               // 0..7
    const int kq   = tid & 3;                // quad lane = K-chunk id = OWN GATE
    const int idx  = (tid >> 2) & 15;
    const int q    = wave * 16 + idx;        // h index 0..127
    const int kbase = kq * 32;               // K-chunk start

    __shared__ __align__(16) float h_s[2][D_LSTM];   // interleaved layout, dbuf

    if (tid < 2 * D_LSTM) ((float*)h_s)[tid] = 0.f;  // h_{-1} = 0 (both bufs)
    __syncthreads();

    // per-thread addresses / constants for the asm block
    const unsigned long long wai = (unsigned long long)(uintptr_t)(W_hh + (size_t)q         * D_LSTM + kbase);
    const unsigned long long waf = (unsigned long long)(uintptr_t)(W_hh + (size_t)(128 + q) * D_LSTM + kbase);
    const unsigned long long wag = (unsigned long long)(uintptr_t)(W_hh + (size_t)(256 + q) * D_LSTM + kbase);
    const unsigned long long wao = (unsigned long long)(uintptr_t)(W_hh + (size_t)(384 + q) * D_LSTM + kbase);
    const unsigned int atid = (unsigned int)(q * 16 + kq * 4);   // byte off of own-gate scalar
    const unsigned int lds0 = (unsigned int)(uintptr_t)&h_s[0][0];
    const unsigned int rd   = lds0 + (unsigned int)(kq * 16);
    const int cc = q >> 2;
    const int p  = ((cc & 7) << 2) | (cc >> 3);                  // interleaved slot
    const unsigned int wr = lds0 + (unsigned int)(p * 16 + (q & 3) * 4);
    const unsigned long long wm  = __ballot(kq == 0);
    const unsigned long long mb0 = __ballot(kq & 1);
    const unsigned long long mb1 = __ballot(kq & 2);
    const float m1 = (kq == 2) ? -2.8853900817779268f  // -2*log2(e)
                               : -1.4426950408889634f; // -log2(e)
    const float sc = (kq == 2) ? 2.0f : 1.0f;
    const float ad = (kq == 2) ? -1.0f : 0.0f;

    asm volatile(
        // ---- prologue: consts + weight loads + A row0 ----
        "s_mov_b32 s80, 2048\n\t"
        "s_mov_b32 s86, 4096\n\t"
        "s_mov_b32 s88, 0xC038AA3B\n\t"     // -2*log2(e)
        "s_mov_b64 s[82:83], %[wm]\n\t"
        "global_load_dwordx4 v[0:3],     %[wai], off\n\t"
        "global_load_dwordx4 v[4:7],     %[wai], off offset:16\n\t"
        "global_load_dwordx4 v[8:11],    %[wai], off offset:32\n\t"
        "global_load_dwordx4 v[12:15],   %[wai], off offset:48\n\t"
        "global_load_dwordx4 v[16:19],   %[wai], off offset:64\n\t"
        "global_load_dwordx4 v[20:23],   %[wai], off offset:80\n\t"
        "global_load_dwordx4 v[24:27],   %[wai], off offset:96\n\t"
        "global_load_dwordx4 v[28:31],   %[wai], off offset:112\n\t"
        "global_load_dwordx4 v[32:35],   %[waf], off\n\t"
        "global_load_dwordx4 v[36:39],   %[waf], off offset:16\n\t"
        "global_load_dwordx4 v[40:43],   %[waf], off offset:32\n\t"
        "global_load_dwordx4 v[44:47],   %[waf], off offset:48\n\t"
        "global_load_dwordx4 v[48:51],   %[waf], off offset:64\n\t"
        "global_load_dwordx4 v[52:55],   %[waf], off offset:80\n\t"
        "global_load_dwordx4 v[56:59],   %[waf], off offset:96\n\t"
        "global_load_dwordx4 v[60:63],   %[waf], off offset:112\n\t"
        "global_load_dwordx4 v[64:67],   %[wag], off\n\t"
        "global_load_dwordx4 v[68:71],   %[wag], off offset:16\n\t"
        "global_load_dwordx4 v[72:75],   %[wag], off offset:32\n\t"
        "global_load_dwordx4 v[76:79],   %[wag], off offset:48\n\t"
        "global_load_dwordx4 v[80:83],   %[wag], off offset:64\n\t"
        "global_load_dwordx4 v[84:87],   %[wag], off offset:80\n\t"
        "global_load_dwordx4 v[88:91],   %[wag], off offset:96\n\t"
        "global_load_dwordx4 v[92:95],   %[wag], off offset:112\n\t"
        "global_load_dwordx4 v[96:99],   %[wao], off\n\t"
        "global_load_dwordx4 v[100:103], %[wao], off offset:16\n\t"
        "global_load_dwordx4 v[104:107], %[wao], off offset:32\n\t"
        "global_load_dwordx4 v[108:111], %[wao], off offset:48\n\t"
        "global_load_dwordx4 v[112:115], %[wao], off offset:64\n\t"
        "global_load_dwordx4 v[116:119], %[wao], off offset:80\n\t"
        "global_load_dwordx4 v[120:123], %[wao], off offset:96\n\t"
        "global_load_dwordx4 v[124:127], %[wao], off offset:112\n\t"
        "global_load_dword v168, %[at], %[ab]\n\t"   // A row 0 (own gate scalar)
        "s_waitcnt vmcnt(0)\n\t"
        "v_mov_b32 v181, 0\n\t"             // c = 0
        "1:\n\t"
        // even step: read buf0 (+0), consume v168, prefetch v172, write buf1 (+512)
        HALF(172, 168, 0,64,128,192,256,320,384,448, 512)
        // odd step: read buf1 (+512), consume v172, prefetch v168, write buf0 (+0)
        HALF(168, 172, 512,576,640,704,768,832,896,960, 0)
        "s_sub_u32 s86, s86, 1\n\t"
        "s_cmp_lg_u32 s86, 0\n\t"
        "s_cbranch_scc1 1b\n\t"
        :
        : [wai]"v"(wai), [waf]"v"(waf), [wag]"v"(wag), [wao]"v"(wao),
          [ab]"s"(A), [at]"v"(atid), [rd]"v"(rd), [wr]"v"(wr), [wm]"s"(wm),
          [mb0]"s"(mb0), [mb1]"s"(mb1), [m1]"v"(m1), [sc]"v"(sc), [ad]"v"(ad)
        : "v0","v1","v2","v3","v4","v5","v6","v7","v8","v9",
          "v10","v11","v12","v13","v14","v15","v16","v17","v18","v19",
          "v20","v21","v22","v23","v24","v25","v26","v27","v28","v29",
          "v30","v31","v32","v33","v34","v35","v36","v37","v38","v39",
          "v40","v41","v42","v43","v44","v45","v46","v47","v48","v49",
          "v50","v51","v52","v53","v54","v55","v56","v57","v58","v59",
          "v60","v61","v62","v63","v64","v65","v66","v67","v68","v69",
          "v70","v71","v72","v73","v74","v75","v76","v77","v78","v79",
          "v80","v81","v82","v83","v84","v85","v86","v87","v88","v89",
          "v90","v91","v92","v93","v94","v95","v96","v97","v98","v99",
          "v100","v101","v102","v103","v104","v105","v106","v107","v108","v109",
          "v110","v111","v112","v113","v114","v115","v116","v117","v118","v119",
          "v120","v121","v122","v123","v124","v125","v126","v127","v128","v129",
          "v130","v131","v132","v133","v134","v135","v136","v137","v138","v139",
          "v140","v141","v142","v143","v144","v145","v146","v147","v148","v149",
          "v150","v151","v152","v153","v154","v155","v156","v157","v158","v159",
          "v160","v161","v162","v163","v164","v165","v166","v167","v168","v169",
          "v170","v171","v172","v173","v174","v175","v176","v177","v178","v179",
          "v180","v181","v182","v183","v184","v185","v186","v187","v188","v189",
          "v190","v191",
          "s80","s81","s82","s83","s84","s85","s86","s87","s88",
          "scc","memory"
    );

    __syncthreads();

    // final FC: out = hT @ W_fc.T + b_fc  (final h in buffer 0, interleaved)
    if (tid < N_CLS) {
        float acc = b_fc[tid];
        #pragma unroll
        for (int k = 0; k < D_LSTM; ++k) {
            const int c2 = k >> 2;
            const int pp = ((c2 & 7) << 2) | (c2 >> 3);
            acc += h_s[0][pp * 4 + (k & 3)] * W_fc[tid * D_LSTM + k];
        }
        out[tid] = acc;
    }
}

// ---------------------------------------------------------------------------
extern "C" void kernel_launch(void* const* d_in, const int* in_sizes, int n_in,
                              void* d_out, int out_size, void* d_ws, size_t ws_size,
                              hipStream_t stream) {
    const float* x       = (const float*)d_in[0];
    const int*   esrc    = (const int*)  d_in[1];
    const int*   edst    = (const int*)  d_in[2];
    const float* W_rel1  = (const float*)d_in[3];
    const float* b_rel1  = (const float*)d_in[4];
    const float* W_root1 = (const float*)d_in[5];
    const float* W_rel2  = (const float*)d_in[6];
    const float* b_rel2  = (const float*)d_in[7];
    const float* W_root2 = (const float*)d_in[8];
    const float* W_ih    = (const float*)d_in[9];
    const float* W_hh    = (const float*)d_in[10];
    const float* b_ih    = (const float*)d_in[11];
    const float* b_hh    = (const float*)d_in[12];
    const float* W_fc    = (const float*)d_in[13];
    const float* b_fc    = (const float*)d_in[14];

    float* out = (float*)d_out;
    float* A   = (float*)d_ws;   // (T,128,4) f32 = 16 MB

    gnn_proj_kernel<<<T_LEN / TB, 64, 0, stream>>>(
        x, esrc, edst, W_rel1, b_rel1, W_root1,
        W_rel2, b_rel2, W_root2, W_ih, b_ih, b_hh, A);

    lstm_kernel<<<1, 512, 0, stream>>>(A, W_hh, W_fc, b_fc, out);
}

// Round 14
// 4460.557 us; speedup vs baseline: 1.4804x; 1.0459x over previous
//
#include <hip/hip_runtime.h>
#include <hip/hip_fp16.h>

#define T_LEN 8192
#define N_NODES 33
#define N_EDGES 64
#define DIM_IN 3
#define D_H 64
#define D_LSTM 128
#define N_CLS 5
#define TB 4   // timesteps per block in kernel 1

typedef float v2f __attribute__((ext_vector_type(2)));
typedef float v4f __attribute__((ext_vector_type(4)));

// ---------------------------------------------------------------------------
// Kernel 1: graph conv x2 + relu + mean over nodes + input-side LSTM projection
// Writes A in (T, 128, 4) layout: A[(t*128+q)*4 + g] = gate g of unit q
// (g: 0=i, 1=f, 2=g, 3=o).  LSTM thread (q,kq) scalar-loads its own gate.
// ---------------------------------------------------------------------------
__global__ __launch_bounds__(64, 2) void gnn_proj_kernel(
    const float* __restrict__ x,        // (T,33,3)
    const int*   __restrict__ esrc,     // (64,)
    const int*   __restrict__ edst,     // (64,)
    const float* __restrict__ W_rel1,   // (64,3)
    const float* __restrict__ b_rel1,   // (64,)
    const float* __restrict__ W_root1,  // (64,3)
    const float* __restrict__ W_rel2,   // (64,64)
    const float* __restrict__ b_rel2,   // (64,)
    const float* __restrict__ W_root2,  // (64,64)
    const float* __restrict__ W_ih,     // (512,64)
    const float* __restrict__ b_ih,     // (512,)
    const float* __restrict__ b_hh,     // (512,)
    float* __restrict__ A)              // (T,128,4)  [workspace]
{
    const int t0 = blockIdx.x * TB;
    const int j  = threadIdx.x;   // 0..63

    __shared__ __align__(16) float x_s[N_NODES][DIM_IN];
    __shared__ __align__(16) float agg1[N_NODES][DIM_IN];
    __shared__ __align__(16) float h1[N_NODES][D_H];
    __shared__ __align__(16) float agg2[N_NODES][D_H];
    __shared__ __align__(16) float seq_s[TB][D_H];
    __shared__ int es[N_EDGES], ed[N_EDGES];

    es[j] = esrc[j];
    ed[j] = edst[j];

    const float wr1_0 = W_rel1[j*3+0], wr1_1 = W_rel1[j*3+1], wr1_2 = W_rel1[j*3+2];
    const float wt1_0 = W_root1[j*3+0], wt1_1 = W_root1[j*3+1], wt1_2 = W_root1[j*3+2];
    const float br1 = b_rel1[j];
    const float br2 = b_rel2[j];

    float wr2[D_H], wt2[D_H];
    #pragma unroll
    for (int k = 0; k < D_H; ++k) {
        wr2[k] = W_rel2[j*D_H + k];
        wt2[k] = W_root2[j*D_H + k];
    }

    for (int tt = 0; tt < TB; ++tt) {
        const int t = t0 + tt;
        __syncthreads();

        const float* xt = x + (size_t)t * (N_NODES * DIM_IN);
        for (int i = j; i < N_NODES * DIM_IN; i += 64) x_s[0][i] = xt[i];
        __syncthreads();

        if (j < N_NODES) {
            float a0 = 0.f, a1 = 0.f, a2 = 0.f;
            for (int e = 0; e < N_EDGES; ++e) {
                if (ed[e] == j) {
                    a0 += x_s[es[e]][0];
                    a1 += x_s[es[e]][1];
                    a2 += x_s[es[e]][2];
                }
            }
            agg1[j][0] = a0; agg1[j][1] = a1; agg1[j][2] = a2;
        }
        __syncthreads();

        for (int n = 0; n < N_NODES; ++n) {
            float v = br1
                + agg1[n][0]*wr1_0 + agg1[n][1]*wr1_1 + agg1[n][2]*wr1_2
                + x_s[n][0]*wt1_0  + x_s[n][1]*wt1_1  + x_s[n][2]*wt1_2;
            h1[n][j]  = v;
            agg2[n][j] = 0.f;
        }
        __syncthreads();

        for (int e = 0; e < N_EDGES; ++e) {
            agg2[ed[e]][j] += h1[es[e]][j];
        }
        __syncthreads();

        float seqv = 0.f;
        for (int n = 0; n < N_NODES; ++n) {
            const float4* ag4 = (const float4*)agg2[n];
            const float4* h4  = (const float4*)h1[n];
            float acc0 = br2, acc1 = 0.f, acc2 = 0.f, acc3 = 0.f;
            #pragma unroll
            for (int k4 = 0; k4 < D_H/4; ++k4) {
                float4 av = ag4[k4];
                float4 hv = h4[k4];
                acc0 += av.x * wr2[4*k4+0] + hv.x * wt2[4*k4+0];
                acc1 += av.y * wr2[4*k4+1] + hv.y * wt2[4*k4+1];
                acc2 += av.z * wr2[4*k4+2] + hv.z * wt2[4*k4+2];
                acc3 += av.w * wr2[4*k4+3] + hv.w * wt2[4*k4+3];
            }
            float acc = (acc0 + acc1) + (acc2 + acc3);
            seqv += fmaxf(acc, 0.f);
        }
        seq_s[tt][j] = seqv * (1.0f / 33.0f);
    }
    __syncthreads();

    #pragma unroll
    for (int m = 0; m < 8; ++m) {
        const int o = m * 64 + j;
        const float bias = b_ih[o] + b_hh[o];
        const float4* w4 = (const float4*)(W_ih + (size_t)o * D_H);
        float acc[TB];
        #pragma unroll
        for (int tt = 0; tt < TB; ++tt) acc[tt] = bias;
        #pragma unroll
        for (int k4 = 0; k4 < D_H/4; ++k4) {
            float4 wv = w4[k4];
            #pragma unroll
            for (int tt = 0; tt < TB; ++tt) {
                const float4* s4 = (const float4*)seq_s[tt];
                float4 sv = s4[k4];
                acc[tt] += sv.x*wv.x + sv.y*wv.y + sv.z*wv.z + sv.w*wv.w;
            }
        }
        // (T,128,4) layout: q = o&127, g = o>>7
        #pragma unroll
        for (int tt = 0; tt < TB; ++tt) {
            A[((size_t)(t0 + tt) * 128 + (o & 127)) * 4 + (o >> 7)] = acc[tt];
        }
    }
}

// ---------------------------------------------------------------------------
// Kernel 2 (round 14): full-asm LSTM with f16 v_dot2_f32_f16 matvec.
//  - r13 measured the f32 pk_fma floor at 512 cyc/step/SIMD; dot2 (2 f16
//    MACs/lane/instr, f32 accumulate) halves it to ~256.
//  - h exchanged as f16: 4 ds_read_b128 per thread (32/step CU-wide, was 64).
//    LDS layout: f16-octet o (h[8o..8o+8)) at slot (o&3)*4 + (o>>2) so read i
//    of thread kq hits slot kq+4i -> 16 distinct banks per instr, no conflict.
//  - weights f32->f16 packed ONCE in the prologue with ISA-safe ops
//    (v_cvt_f16_f32 + and/lshl/or).  h written per step via v_cvt_f16_f32 +
//    ds_write_b16.
//  - reduce / nonlinearity / A-scalar path byte-identical to r13 (proven);
//    the pk-half fold disappears (accs are scalar f32 v160-163).
// Register map: v0-63 packed f16 weights | v128-143 h (f16 pairs) |
// v160-163 accs | v168/v172 A dbuf | v176-190 temps | v181 c.
// ---------------------------------------------------------------------------

#define CVTPK(D,S0,S1) \
  "v_cvt_f16_f32 v190, v" #S0 "\n\t" \
  "v_cvt_f16_f32 v191, v" #S1 "\n\t" \
  "v_and_b32 v190, 0xffff, v190\n\t" \
  "v_lshlrev_b32 v191, 16, v191\n\t" \
  "v_or_b32 v" #D ", v190, v191\n\t"

#define ROWPACK(D0,D1,D2,D3,D4,D5,D6,D7,D8,D9,D10,D11,D12,D13,D14,D15) \
  CVTPK(D0,128,129) CVTPK(D1,130,131) CVTPK(D2,132,133) CVTPK(D3,134,135) \
  CVTPK(D4,136,137) CVTPK(D5,138,139) CVTPK(D6,140,141) CVTPK(D7,142,143) \
  CVTPK(D8,144,145) CVTPK(D9,146,147) CVTPK(D10,148,149) CVTPK(D11,150,151) \
  CVTPK(D12,152,153) CVTPK(D13,154,155) CVTPK(D14,156,157) CVTPK(D15,158,159)

#define ROWLOAD(WA) \
  "global_load_dwordx4 v[128:131], %[" #WA "], off\n\t" \
  "global_load_dwordx4 v[132:135], %[" #WA "], off offset:16\n\t" \
  "global_load_dwordx4 v[136:139], %[" #WA "], off offset:32\n\t" \
  "global_load_dwordx4 v[140:143], %[" #WA "], off offset:48\n\t" \
  "global_load_dwordx4 v[144:147], %[" #WA "], off offset:64\n\t" \
  "global_load_dwordx4 v[148:151], %[" #WA "], off offset:80\n\t" \
  "global_load_dwordx4 v[152:155], %[" #WA "], off offset:96\n\t" \
  "global_load_dwordx4 v[156:159], %[" #WA "], off offset:112\n\t" \
  "s_waitcnt vmcnt(0)\n\t"

// 4 dot2 (one per gate) for h dword H against weight dwords A,B,C,D
#define DOT4(H, A,B,C,D) \
  "v_dot2_f32_f16 v160, v" #H ", v" #A ", v160\n\t" \
  "v_dot2_f32_f16 v161, v" #H ", v" #B ", v161\n\t" \
  "v_dot2_f32_f16 v162, v" #H ", v" #C ", v162\n\t" \
  "v_dot2_f32_f16 v163, v" #H ", v" #D ", v163\n\t"
#define DOT4Z(H, A,B,C,D) \
  "v_dot2_f32_f16 v160, v" #H ", v" #A ", 0\n\t" \
  "v_dot2_f32_f16 v161, v" #H ", v" #B ", 0\n\t" \
  "v_dot2_f32_f16 v162, v" #H ", v" #C ", 0\n\t" \
  "v_dot2_f32_f16 v163, v" #H ", v" #D ", 0\n\t"

// P = prefetch dest reg (next step's A), PC = consume reg (this step's A)
#define HALF(P, PC, R0,R1,R2,R3, WOFF) \
  "v_add_u32 v190, s80, %[at]\n\t" \
  "global_load_dword v" #P ", v190, %[ab]\n\t" \
  "s_add_u32 s80, s80, 2048\n\t" \
  "s_cmp_lg_u32 s80, 0x1000000\n\t" \
  "s_cselect_b32 s80, s80, 0\n\t" \
  "ds_read_b128 v[128:131], %[rd] offset:" #R0 "\n\t" \
  "ds_read_b128 v[132:135], %[rd] offset:" #R1 "\n\t" \
  "ds_read_b128 v[136:139], %[rd] offset:" #R2 "\n\t" \
  "ds_read_b128 v[140:143], %[rd] offset:" #R3 "\n\t" \
  "s_waitcnt lgkmcnt(2)\n\t" \
  DOT4Z(128, 0,16,32,48) \
  DOT4(129, 1,17,33,49) \
  DOT4(130, 2,18,34,50) \
  DOT4(131, 3,19,35,51) \
  DOT4(132, 4,20,36,52) \
  DOT4(133, 5,21,37,53) \
  DOT4(134, 6,22,38,54) \
  DOT4(135, 7,23,39,55) \
  "s_waitcnt lgkmcnt(0)\n\t" \
  DOT4(136, 8,24,40,56) \
  DOT4(137, 9,25,41,57) \
  DOT4(138, 10,26,42,58) \
  DOT4(139, 11,27,43,59) \
  DOT4(140, 12,28,44,60) \
  DOT4(141, 13,29,45,61) \
  DOT4(142, 14,30,46,62) \
  DOT4(143, 15,31,47,63) \
  /* quad reduce-scatter: accs v160=i v161=f v162=g v163=o */ \
  "v_mov_b32_dpp v184, v160 quad_perm:[2,3,0,1] row_mask:0xf bank_mask:0xf\n\t" \
  "v_mov_b32_dpp v185, v161 quad_perm:[2,3,0,1] row_mask:0xf bank_mask:0xf\n\t" \
  "v_mov_b32_dpp v186, v162 quad_perm:[2,3,0,1] row_mask:0xf bank_mask:0xf\n\t" \
  "v_mov_b32_dpp v187, v163 quad_perm:[2,3,0,1] row_mask:0xf bank_mask:0xf\n\t" \
  "v_add_f32 v160, v160, v184\n\t" \
  "v_add_f32 v161, v161, v185\n\t" \
  "v_add_f32 v162, v162, v186\n\t" \
  "v_add_f32 v163, v163, v187\n\t" \
  "v_cndmask_b32 v184, v160, v162, %[mb1]\n\t" \
  "v_cndmask_b32 v185, v161, v163, %[mb1]\n\t" \
  "s_nop 1\n\t" \
  "v_mov_b32_dpp v186, v184 quad_perm:[1,0,3,2] row_mask:0xf bank_mask:0xf\n\t" \
  "v_mov_b32_dpp v187, v185 quad_perm:[1,0,3,2] row_mask:0xf bank_mask:0xf\n\t" \
  "v_add_f32 v184, v184, v186\n\t" \
  "v_add_f32 v185, v185, v187\n\t" \
  "v_cndmask_b32 v184, v184, v185, %[mb0]\n\t"   /* lane kq: sum of gate kq */ \
  "s_waitcnt vmcnt(1)\n\t" \
  "v_add_f32 v184, v184, v" #PC "\n\t" \
  /* per-lane nonlin: y=rcp(1+exp2(m1*x)); y'=y*sc+ad */ \
  "v_mul_f32 v186, %[m1], v184\n\t" \
  "v_exp_f32 v186, v186\n\t" \
  "s_nop 1\n\t" \
  "v_add_f32 v186, 1.0, v186\n\t" \
  "v_rcp_f32 v186, v186\n\t" \
  "s_nop 1\n\t" \
  "v_fma_f32 v186, v186, %[sc], %[ad]\n\t" \
  "s_nop 1\n\t" \
  /* quad broadcast: si,sf,tg,so */ \
  "v_mov_b32_dpp v176, v186 quad_perm:[0,0,0,0] row_mask:0xf bank_mask:0xf\n\t" \
  "v_mov_b32_dpp v177, v186 quad_perm:[1,1,1,1] row_mask:0xf bank_mask:0xf\n\t" \
  "v_mov_b32_dpp v179, v186 quad_perm:[2,2,2,2] row_mask:0xf bank_mask:0xf\n\t" \
  "v_mov_b32_dpp v178, v186 quad_perm:[3,3,3,3] row_mask:0xf bank_mask:0xf\n\t" \
  /* c = sf*c + si*tg */ \
  "v_mul_f32 v180, v176, v179\n\t" \
  "v_fma_f32 v181, v177, v181, v180\n\t" \
  /* tanh(c) */ \
  "v_mul_f32 v182, s88, v181\n\t" \
  "v_exp_f32 v182, v182\n\t" \
  "s_nop 1\n\t" \
  "v_add_f32 v182, 1.0, v182\n\t" \
  "v_rcp_f32 v182, v182\n\t" \
  "s_nop 1\n\t" \
  "v_fma_f32 v182, v182, 2.0, -1.0\n\t" \
  "v_mul_f32 v183, v178, v182\n\t" \
  "v_cvt_f16_f32 v183, v183\n\t" \
  /* write h as f16 (kq==0 lanes) */ \
  "s_and_saveexec_b64 s[84:85], s[82:83]\n\t" \
  "ds_write_b16 %[wr], v183 offset:" #WOFF "\n\t" \
  "s_mov_b64 exec, s[84:85]\n\t" \
  "s_waitcnt lgkmcnt(0)\n\t" \
  "s_barrier\n\t"

__global__ __launch_bounds__(512, 2)
__attribute__((amdgpu_waves_per_eu(2, 2)))
void lstm_kernel(
    const float* __restrict__ A,      // (T,128,4)
    const float* __restrict__ W_hh,   // (512,128)
    const float* __restrict__ W_fc,   // (5,128)
    const float* __restrict__ b_fc,   // (5,)
    float* __restrict__ out)          // (5,)
{
    const int tid  = threadIdx.x;            // 0..511
    const int wave = tid >> 6;               // 0..7
    const int kq   = tid & 3;                // quad lane = K-chunk id = OWN GATE
    const int idx  = (tid >> 2) & 15;
    const int q    = wave * 16 + idx;        // h index 0..127
    const int kbase = kq * 32;               // K-chunk start (f32 elements)

    // h as f16: 2 buffers x 128 f16 = 2 x 256B; slot layout below
    __shared__ __align__(16) float h_s[2][64];

    if (tid < 128) ((float*)h_s)[tid] = 0.f;  // h_{-1} = 0 (both bufs, f16 0)
    __syncthreads();

    // per-thread addresses / constants for the asm block
    const unsigned long long wai = (unsigned long long)(uintptr_t)(W_hh + (size_t)q         * D_LSTM + kbase);
    const unsigned long long waf = (unsigned long long)(uintptr_t)(W_hh + (size_t)(128 + q) * D_LSTM + kbase);
    const unsigned long long wag = (unsigned long long)(uintptr_t)(W_hh + (size_t)(256 + q) * D_LSTM + kbase);
    const unsigned long long wao = (unsigned long long)(uintptr_t)(W_hh + (size_t)(384 + q) * D_LSTM + kbase);
    const unsigned int atid = (unsigned int)(q * 16 + kq * 4);   // byte off of own-gate scalar
    const unsigned int lds0 = (unsigned int)(uintptr_t)&h_s[0][0];
    const unsigned int rd   = lds0 + (unsigned int)(kq * 16);
    // write position: octet o=q>>3 at slot (o&3)*4+(o>>2), halfword q&7
    const int o  = q >> 3;
    const int sl = ((o & 3) << 2) | (o >> 2);
    const unsigned int wr = lds0 + (unsigned int)(sl * 16 + (q & 7) * 2);
    const unsigned long long wm  = __ballot(kq == 0);
    const unsigned long long mb0 = __ballot(kq & 1);
    const unsigned long long mb1 = __ballot(kq & 2);
    const float m1 = (kq == 2) ? -2.8853900817779268f  // -2*log2(e)
                               : -1.4426950408889634f; // -log2(e)
    const float sc = (kq == 2) ? 2.0f : 1.0f;
    const float ad = (kq == 2) ? -1.0f : 0.0f;

    asm volatile(
        // ---- prologue: consts; load f32 weight rows; pack to f16 v0-63 ----
        "s_mov_b32 s80, 2048\n\t"
        "s_mov_b32 s86, 4096\n\t"
        "s_mov_b32 s88, 0xC038AA3B\n\t"     // -2*log2(e)
        "s_mov_b64 s[82:83], %[wm]\n\t"
        ROWLOAD(wai)
        ROWPACK(0,1,2,3,4,5,6,7,8,9,10,11,12,13,14,15)
        ROWLOAD(waf)
        ROWPACK(16,17,18,19,20,21,22,23,24,25,26,27,28,29,30,31)
        ROWLOAD(wag)
        ROWPACK(32,33,34,35,36,37,38,39,40,41,42,43,44,45,46,47)
        ROWLOAD(wao)
        ROWPACK(48,49,50,51,52,53,54,55,56,57,58,59,60,61,62,63)
        "global_load_dword v168, %[at], %[ab]\n\t"   // A row 0 (own gate scalar)
        "s_waitcnt vmcnt(0)\n\t"
        "v_mov_b32 v181, 0\n\t"             // c = 0
        "1:\n\t"
        // even step: read buf0 (+0), consume v168, prefetch v172, write buf1 (+256)
        HALF(172, 168, 0,64,128,192, 256)
        // odd step: read buf1 (+256), consume v172, prefetch v168, write buf0 (+0)
        HALF(168, 172, 256,320,384,448, 0)
        "s_sub_u32 s86, s86, 1\n\t"
        "s_cmp_lg_u32 s86, 0\n\t"
        "s_cbranch_scc1 1b\n\t"
        :
        : [wai]"v"(wai), [waf]"v"(waf), [wag]"v"(wag), [wao]"v"(wao),
          [ab]"s"(A), [at]"v"(atid), [rd]"v"(rd), [wr]"v"(wr), [wm]"s"(wm),
          [mb0]"s"(mb0), [mb1]"s"(mb1), [m1]"v"(m1), [sc]"v"(sc), [ad]"v"(ad)
        : "v0","v1","v2","v3","v4","v5","v6","v7","v8","v9",
          "v10","v11","v12","v13","v14","v15","v16","v17","v18","v19",
          "v20","v21","v22","v23","v24","v25","v26","v27","v28","v29",
          "v30","v31","v32","v33","v34","v35","v36","v37","v38","v39",
          "v40","v41","v42","v43","v44","v45","v46","v47","v48","v49",
          "v50","v51","v52","v53","v54","v55","v56","v57","v58","v59",
          "v60","v61","v62","v63","v64","v65","v66","v67","v68","v69",
          "v70","v71","v72","v73","v74","v75","v76","v77","v78","v79",
          "v80","v81","v82","v83","v84","v85","v86","v87","v88","v89",
          "v90","v91","v92","v93","v94","v95","v96","v97","v98","v99",
          "v100","v101","v102","v103","v104","v105","v106","v107","v108","v109",
          "v110","v111","v112","v113","v114","v115","v116","v117","v118","v119",
          "v120","v121","v122","v123","v124","v125","v126","v127","v128","v129",
          "v130","v131","v132","v133","v134","v135","v136","v137","v138","v139",
          "v140","v141","v142","v143","v144","v145","v146","v147","v148","v149",
          "v150","v151","v152","v153","v154","v155","v156","v157","v158","v159",
          "v160","v161","v162","v163","v164","v165","v166","v167","v168","v169",
          "v170","v171","v172","v173","v174","v175","v176","v177","v178","v179",
          "v180","v181","v182","v183","v184","v185","v186","v187","v188","v189",
          "v190","v191",
          "s80","s81","s82","s83","s84","s85","s86","s87","s88",
          "scc","memory"
    );

    __syncthreads();

    // final FC: out = hT @ W_fc.T + b_fc  (final h in buffer 0, f16, slotted)
    if (tid < N_CLS) {
        const __half* hh = (const __half*)&h_s[0][0];
        float acc = b_fc[tid];
        #pragma unroll
        for (int k = 0; k < D_LSTM; ++k) {
            const int o2  = k >> 3;
            const int sl2 = ((o2 & 3) << 2) | (o2 >> 2);
            acc += __half2float(hh[sl2 * 8 + (k & 7)]) * W_fc[tid * D_LSTM + k];
        }
        out[tid] = acc;
    }
}

// ---------------------------------------------------------------------------
extern "C" void kernel_launch(void* const* d_in, const int* in_sizes, int n_in,
                              void* d_out, int out_size, void* d_ws, size_t ws_size,
                              hipStream_t stream) {
    const float* x       = (const float*)d_in[0];
    const int*   esrc    = (const int*)  d_in[1];
    const int*   edst    = (const int*)  d_in[2];
    const float* W_rel1  = (const float*)d_in[3];
    const float* b_rel1  = (const float*)d_in[4];
    const float* W_root1 = (const float*)d_in[5];
    const float* W_rel2  = (const float*)d_in[6];
    const float* b_rel2  = (const float*)d_in[7];
    const float* W_root2 = (const float*)d_in[8];
    const float* W_ih    = (const float*)d_in[9];
    const float* W_hh    = (const float*)d_in[10];
    const float* b_ih    = (const float*)d_in[11];
    const float* b_hh    = (const float*)d_in[12];
    const float* W_fc    = (const float*)d_in[13];
    const float* b_fc    = (const float*)d_in[14];

    float* out = (float*)d_out;
    float* A   = (float*)d_ws;   // (T,128,4) f32 = 16 MB

    gnn_proj_kernel<<<T_LEN / TB, 64, 0, stream>>>(
        x, esrc, edst, W_rel1, b_rel1, W_root1,
        W_rel2, b_rel2, W_root2, W_ih, b_ih, b_hh, A);

    lstm_kernel<<<1, 512, 0, stream>>>(A, W_hh, W_fc, b_fc, out);
}